// Round 17
// baseline (644.314 us; speedup 1.0000x reference)
//
#include <hip/hip_runtime.h>
#include <stdint.h>

// Problem constants (ConvLayer_58007828300270)
#define B_   2
#define S_   4096
#define D_   2048
#define DI_  4096
#define M_   (B_ * S_)   // 8192 rows
#define EPS_ 1e-5f
#define SCH_ 8           // conv: s-rows per thread

typedef __bf16 bf16x8 __attribute__((ext_vector_type(8)));
typedef float  f32x4  __attribute__((ext_vector_type(4)));
typedef uint16_t u16x8 __attribute__((ext_vector_type(8)));

__device__ __forceinline__ uint16_t f32_to_bf16(float f) {
    uint32_t u = __builtin_bit_cast(uint32_t, f);
    uint32_t r = (u + 0x7fffu + ((u >> 16) & 1u)) >> 16;   // RNE
    return (uint16_t)r;
}
__device__ __forceinline__ float bf16_to_f32(uint16_t h) {
    return __builtin_bit_cast(float, (uint32_t)h << 16);
}

typedef const __attribute__((address_space(1))) uint32_t* gptr_t;
typedef __attribute__((address_space(3))) uint32_t* lptr_t;

// async global->LDS, 16B per lane, dst = wave-uniform base + lane*16
__device__ __forceinline__ void gll16(const void* g, void* l) {
    __builtin_amdgcn_global_load_lds((gptr_t)g, (lptr_t)l, 16, 0, 0);
}

// ---------------------------------------------------------------------------
// Transpose + f32->bf16 convert: W[K][N] f32 -> WT[N][K] bf16. 32x32 tiles.
// ---------------------------------------------------------------------------
__global__ __launch_bounds__(256)
void transpose_bf16_kernel(const float* __restrict__ W, uint16_t* __restrict__ WT,
                           int K, int N) {
    __shared__ float tile[32][33];
    const int nb = N / 32;
    const int tn = blockIdx.x % nb;
    const int tk = blockIdx.x / nb;
    const int tx = threadIdx.x & 31;
    const int ty = threadIdx.x >> 5;          // 0..7
    const int gk = tk * 32, gn = tn * 32;
#pragma unroll
    for (int i = 0; i < 4; i++) {
        int k = ty + i * 8;
        tile[k][tx] = W[(size_t)(gk + k) * N + gn + tx];
    }
    __syncthreads();
#pragma unroll
    for (int i = 0; i < 4; i++) {
        int n = ty + i * 8;
        WT[(size_t)(gn + n) * K + gk + tx] = f32_to_bf16(tile[tx][n]);
    }
}

// ---------------------------------------------------------------------------
// RMSNorm: one block per row, 256 threads x 8 elems. f32 in -> bf16 out.
// ---------------------------------------------------------------------------
__global__ __launch_bounds__(256)
void rmsnorm_kernel(const float* __restrict__ x, const float* __restrict__ w,
                    uint16_t* __restrict__ out) {
    const int row  = blockIdx.x;
    const int tid  = threadIdx.x;
    const int lane = tid & 63, wid = tid >> 6;
    const float* xr = x + (size_t)row * D_;

    f32x4 a = *(const f32x4*)&xr[tid * 8];
    f32x4 b = *(const f32x4*)&xr[tid * 8 + 4];
    float ss = a[0]*a[0] + a[1]*a[1] + a[2]*a[2] + a[3]*a[3]
             + b[0]*b[0] + b[1]*b[1] + b[2]*b[2] + b[3]*b[3];
#pragma unroll
    for (int off = 32; off > 0; off >>= 1) ss += __shfl_xor(ss, off);

    __shared__ float red[4];
    if (lane == 0) red[wid] = ss;
    __syncthreads();
    const float tot = red[0] + red[1] + red[2] + red[3];
    const float scale = rsqrtf(tot * (1.0f / D_) + EPS_);

    f32x4 wa = *(const f32x4*)&w[tid * 8];
    f32x4 wb = *(const f32x4*)&w[tid * 8 + 4];
    u16x8 o;
#pragma unroll
    for (int j = 0; j < 4; j++) o[j]     = f32_to_bf16(a[j] * scale * wa[j]);
#pragma unroll
    for (int j = 0; j < 4; j++) o[j + 4] = f32_to_bf16(b[j] * scale * wb[j]);
    *(u16x8*)&out[(size_t)row * D_ + tid * 8] = o;
}

// ---------------------------------------------------------------------------
// 128x128 GEMM, 4 phases/K-tile (BK=64), 256 thr = 4 waves (2M x 2N),
// 64 KiB LDS -> 2 BLOCKS/CU (R16 experiment: cross-block anti-phase overlap,
// m114 mechanism — two independent barrier groups per CU let one block's
// MFMA phase hide the other's ds_read phase; R14's 1-block/CU lockstep
// measured wall == serial LDS+MFMA sum).
// Ledger = R14 verbatim (slot structure, single vmcnt(6)/K-tile, 1 barrier/
// phase), indices re-derived for 128^2:
//   per wave 64x64 out = 4x4 frags 16x16; phases p1: A mh{0,1}+B n{0,1},
//   p2: B n{2,3}, p3: A mh{2,3}, p4: none; 8 MFMA/phase.
//   A region i = rows 32i..+31; Ah0={0,2} (rows wr*64..+31), Ah1={1,3}.
//   B LDS row rho = h*64 + q*32 + j for logical col q*64+h*32+j;
//   Bh0 = regions {0,1}, Bh1 = {2,3}; frag row rho_n = (n>>1)*64+wc*32+(n&1)*16+fr.
// Stage slots: p1: Bh0(t+1)->nxt  p2: Ah0(t+2)->cur  p3: Bh1(t+2)->cur
//              p4: Ah1(t+2)->cur; single wait end-p4 vmcnt(6) (tail 0).
// FIFO: 6 outstanding entering each tile (hand-retraced; same as R14).
// WAR: each staged region's last read is bounded by the immediately
// preceding barrier (p2 vs p1-reads, p3 vs p2-reads, p4 vs p3-reads).
// Block schedule: XCD x owns an (nbn/8)-col B-strip; 64 concurrent
// blocks/XCD (2/CU) form (64>>wlog) rows x wc_ cols per round.
// EPI: 0 = f32 out + residual add
//      3 = fused up/gate: col<DI_ -> Cb (bf16), col>=DI_ -> silu -> Cb2.
// ---------------------------------------------------------------------------
template <int EPI>
__global__ __launch_bounds__(256, 2)
void gemm8p_kernel(const uint16_t* __restrict__ A, const uint16_t* __restrict__ BT,
                   int M, int N, int K,
                   float* __restrict__ Cf, uint16_t* __restrict__ Cb,
                   uint16_t* __restrict__ Cb2, const float* __restrict__ resid) {
    __shared__ uint16_t As[2][8192];   // 2 x 16 KiB (128 rows x 64 bf16)
    __shared__ uint16_t Bs[2][8192];

    const int nbn = N >> 7;
    const int bid = blockIdx.x;
    // L2/L3-aware schedule: xcd = bid&7 owns cols [xcd*wc_, +wc_);
    // 64 concurrent blocks per XCD (2/CU).
    const int xcd = bid & 7;
    const int j   = bid >> 3;
    const int wc_ = nbn >> 3;                 // cols per XCD; pow2
    const int wlog = 31 - __clz(wc_);
    const int g   = j >> 6;
    const int rr  = j & 63;
    const int bm  = g * (64 >> wlog) + (rr >> wlog);
    const int bn  = (xcd << wlog) + (rr & (wc_ - 1));

    const int brow = bm << 7, bcol = bn << 7;
    const int tid  = threadIdx.x;
    const int wid  = tid >> 6, lane = tid & 63;
    const int wr   = wid >> 1, wc = wid & 1;     // 2x2 wave grid
    const int fr   = lane & 15;
    // swizzled k-offset within a 64-elem row (involution on bits 3..5)
    const int kx0 = (((lane >> 4) << 3)) ^ ((lane & 7) << 3);
    const int kx1 = kx0 ^ 32;
    // B fragment LDS rows: rho_n = (n>>1)*64 + wc*32 + (n&1)*16 + fr
    int rhoN[4];
#pragma unroll
    for (int n = 0; n < 4; n++) rhoN[n] = ((n >> 1) << 6) + (wc << 5) + ((n & 1) << 4) + fr;

    // staging source descriptors: call i covers LDS bytes [i*4096, i*4096+4096)
    const uint16_t* ApS[4];
    const uint16_t* BpS[4];
#pragma unroll
    for (int i = 0; i < 4; i++) {
        const int z  = (i << 12) + (wid << 10) + (lane << 4);
        const int zz = z ^ (((z >> 7) & 7) << 4);
        const int row = zz >> 7;           // LDS row = logical A row (0..127)
        const int kk  = (zz >> 1) & 63;
        ApS[i] = A + (size_t)(brow + row) * K + kk;
        // B: LDS row rho -> logical col r = q*64 + h*32 + jj
        const int h = row >> 6, q = (row >> 5) & 1, jj = row & 31;
        BpS[i] = BT + (size_t)(bcol + q * 64 + h * 32 + jj) * K + kk;
    }

    f32x4 acc[4][4];
#pragma unroll
    for (int i = 0; i < 4; i++)
#pragma unroll
        for (int jn = 0; jn < 4; jn++) acc[i][jn] = (f32x4){0.f, 0.f, 0.f, 0.f};

    const int nt = K >> 6;

    // ---- prologue: 7 halves (FIFO leaves steady-state 6 in flight) ----
    gll16(ApS[0],      &As[0][0 * 2048 + wid * 512]);   // Ah0(0)
    gll16(ApS[2],      &As[0][2 * 2048 + wid * 512]);
    gll16(BpS[0],      &Bs[0][0 * 2048 + wid * 512]);   // Bh0(0)
    gll16(BpS[1],      &Bs[0][1 * 2048 + wid * 512]);
    gll16(BpS[2],      &Bs[0][2 * 2048 + wid * 512]);   // Bh1(0)
    gll16(BpS[3],      &Bs[0][3 * 2048 + wid * 512]);
    gll16(ApS[1],      &As[0][1 * 2048 + wid * 512]);   // Ah1(0)
    gll16(ApS[3],      &As[0][3 * 2048 + wid * 512]);
    gll16(ApS[0] + 64, &As[1][0 * 2048 + wid * 512]);   // Ah0(1)
    gll16(ApS[2] + 64, &As[1][2 * 2048 + wid * 512]);
    gll16(BpS[2] + 64, &Bs[1][2 * 2048 + wid * 512]);   // Bh1(1)
    gll16(BpS[3] + 64, &Bs[1][3 * 2048 + wid * 512]);
    gll16(ApS[1] + 64, &As[1][1 * 2048 + wid * 512]);   // Ah1(1)
    gll16(ApS[3] + 64, &As[1][3 * 2048 + wid * 512]);
    asm volatile("s_waitcnt vmcnt(6)" ::: "memory");     // tile 0 fully landed
    __builtin_amdgcn_s_barrier();

    bf16x8 aF[4], bF[8];

    for (int t = 0; t < nt; ++t) {
        const int cur = t & 1, nxt = cur ^ 1;
        const int kn1 = (t + 1) << 6;
        const int kn2 = (t + 2) << 6;
        const bool pf1 = (t + 1) < nt;
        const bool pf2 = (t + 2) < nt;

        // ---- p1: read A mh{0,1} + B n{0,1}; stage Bh0(t+1)->nxt; MFMA mh01xn01
#pragma unroll
        for (int mh = 0; mh < 2; ++mh) {
            const int r = (wr << 6) + (mh << 4) + fr;
            aF[mh * 2 + 0] = *(const bf16x8*)&As[cur][r * 64 + kx0];
            aF[mh * 2 + 1] = *(const bf16x8*)&As[cur][r * 64 + kx1];
        }
#pragma unroll
        for (int n = 0; n < 2; ++n) {
            bF[n * 2 + 0] = *(const bf16x8*)&Bs[cur][rhoN[n] * 64 + kx0];
            bF[n * 2 + 1] = *(const bf16x8*)&Bs[cur][rhoN[n] * 64 + kx1];
        }
        if (pf1) {
            gll16(BpS[0] + kn1, &Bs[nxt][0 * 2048 + wid * 512]);
            gll16(BpS[1] + kn1, &Bs[nxt][1 * 2048 + wid * 512]);
        }
        __builtin_amdgcn_s_setprio(1);
#pragma unroll
        for (int mh = 0; mh < 2; ++mh)
#pragma unroll
            for (int n = 0; n < 2; ++n)
#pragma unroll
                for (int ks = 0; ks < 2; ++ks)
                    acc[mh][n] = __builtin_amdgcn_mfma_f32_16x16x32_bf16(
                        aF[mh * 2 + ks], bF[n * 2 + ks], acc[mh][n], 0, 0, 0);
        __builtin_amdgcn_s_setprio(0);
        __builtin_amdgcn_s_barrier();

        // ---- p2: read B n{2,3}; stage Ah0(t+2)->cur; MFMA mh01xn23
#pragma unroll
        for (int n = 2; n < 4; ++n) {
            bF[n * 2 + 0] = *(const bf16x8*)&Bs[cur][rhoN[n] * 64 + kx0];
            bF[n * 2 + 1] = *(const bf16x8*)&Bs[cur][rhoN[n] * 64 + kx1];
        }
        if (pf2) {
            gll16(ApS[0] + kn2, &As[cur][0 * 2048 + wid * 512]);
            gll16(ApS[2] + kn2, &As[cur][2 * 2048 + wid * 512]);
        }
        __builtin_amdgcn_s_setprio(1);
#pragma unroll
        for (int mh = 0; mh < 2; ++mh)
#pragma unroll
            for (int n = 2; n < 4; ++n)
#pragma unroll
                for (int ks = 0; ks < 2; ++ks)
                    acc[mh][n] = __builtin_amdgcn_mfma_f32_16x16x32_bf16(
                        aF[mh * 2 + ks], bF[n * 2 + ks], acc[mh][n], 0, 0, 0);
        __builtin_amdgcn_s_setprio(0);
        __builtin_amdgcn_s_barrier();

        // ---- p3: read A mh{2,3}; stage Bh1(t+2)->cur; MFMA mh23xn23
#pragma unroll
        for (int mh = 0; mh < 2; ++mh) {
            const int r = (wr << 6) + 32 + (mh << 4) + fr;
            aF[mh * 2 + 0] = *(const bf16x8*)&As[cur][r * 64 + kx0];
            aF[mh * 2 + 1] = *(const bf16x8*)&As[cur][r * 64 + kx1];
        }
        if (pf2) {
            gll16(BpS[2] + kn2, &Bs[cur][2 * 2048 + wid * 512]);
            gll16(BpS[3] + kn2, &Bs[cur][3 * 2048 + wid * 512]);
        }
        __builtin_amdgcn_s_setprio(1);
#pragma unroll
        for (int mh = 0; mh < 2; ++mh)
#pragma unroll
            for (int n = 2; n < 4; ++n)
#pragma unroll
                for (int ks = 0; ks < 2; ++ks)
                    acc[2 + mh][n] = __builtin_amdgcn_mfma_f32_16x16x32_bf16(
                        aF[mh * 2 + ks], bF[n * 2 + ks], acc[2 + mh][n], 0, 0, 0);
        __builtin_amdgcn_s_setprio(0);
        __builtin_amdgcn_s_barrier();

        // ---- p4: stage Ah1(t+2)->cur; MFMA mh23xn01; SINGLE wait
        if (pf2) {
            gll16(ApS[1] + kn2, &As[cur][1 * 2048 + wid * 512]);
            gll16(ApS[3] + kn2, &As[cur][3 * 2048 + wid * 512]);
        }
        __builtin_amdgcn_s_setprio(1);
#pragma unroll
        for (int mh = 0; mh < 2; ++mh)
#pragma unroll
            for (int n = 0; n < 2; ++n)
#pragma unroll
                for (int ks = 0; ks < 2; ++ks)
                    acc[2 + mh][n] = __builtin_amdgcn_mfma_f32_16x16x32_bf16(
                        aF[mh * 2 + ks], bF[n * 2 + ks], acc[2 + mh][n], 0, 0, 0);
        __builtin_amdgcn_s_setprio(0);
        if (pf2) { asm volatile("s_waitcnt vmcnt(6)" ::: "memory"); }
        else     { asm volatile("s_waitcnt vmcnt(0)" ::: "memory"); }
        __builtin_amdgcn_s_barrier();
    }

    // epilogue: C/D layout col = lane&15, row = (lane>>4)*4 + reg
    const int r0 = (lane >> 4) << 2;
    const bool upHalf = (bcol < DI_);   // block-uniform for EPI==3 (DI_%128==0)
#pragma unroll
    for (int mh = 0; mh < 4; ++mh) {
        const int row = brow + (wr << 6) + (mh << 4) + r0;
#pragma unroll
        for (int n = 0; n < 4; ++n) {
            const int col = bcol + (wc << 6) + (n << 4) + fr;
#pragma unroll
            for (int r = 0; r < 4; ++r) {
                const float v = acc[mh][n][r];
                if (EPI == 0) {
                    const size_t idx = (size_t)(row + r) * N + col;
                    Cf[idx] = v + resid[idx];
                } else {  // EPI == 3: fused up/gate routing
                    if (upHalf) {
                        Cb[(size_t)(row + r) * DI_ + col] = f32_to_bf16(v);
                    } else {
                        const float s = v / (1.0f + __expf(-v));
                        Cb2[(size_t)(row + r) * DI_ + (col - DI_)] = f32_to_bf16(s);
                    }
                }
            }
        }
    }
}

// ---------------------------------------------------------------------------
// Causal depthwise conv (K=4) on `up`, multiply by silu-gate (in sg),
// write gated back into sg (in place, element-wise safe).
// ---------------------------------------------------------------------------
__global__ __launch_bounds__(256)
void conv_mul_kernel(const uint16_t* __restrict__ up, uint16_t* __restrict__ sg,
                     const float* __restrict__ cw, const float* __restrict__ cb) {
    const size_t gid = (size_t)blockIdx.x * 256 + threadIdx.x;
    const int c8 = (int)(gid % (DI_ / 8));                 // channel group, fastest
    const int sc = (int)((gid / (DI_ / 8)) % (S_ / SCH_)); // s-chunk
    const int b  = (int)(gid / ((size_t)(DI_ / 8) * (S_ / SCH_)));
    const int c0 = c8 * 8;
    const int s0 = sc * SCH_;

    f32x4 wv[8];
#pragma unroll
    for (int j = 0; j < 8; j++) wv[j] = *(const f32x4*)&cw[(c0 + j) * 4];
    const f32x4 b0 = *(const f32x4*)&cb[c0];
    const f32x4 b1 = *(const f32x4*)&cb[c0 + 4];

    const uint16_t* upb = up + (size_t)b * S_ * DI_ + c0;
    uint16_t*       sgb = sg + (size_t)b * S_ * DI_ + c0;

    u16x8 win[3];
#pragma unroll
    for (int i = 0; i < 3; i++) {
        const int ss = s0 - 3 + i;
        if (ss >= 0) {
            win[i] = *(const u16x8*)&upb[(size_t)ss * DI_];
        } else {
#pragma unroll
            for (int j = 0; j < 8; j++) win[i][j] = 0;
        }
    }

#pragma unroll
    for (int st = 0; st < SCH_; ++st) {
        const size_t roff = (size_t)(s0 + st) * DI_;
        const u16x8 curv = *(const u16x8*)&upb[roff];
        const u16x8 gv   = *(const u16x8*)&sgb[roff];
        u16x8 o;
#pragma unroll
        for (int j = 0; j < 8; j++) {
            const float bias = (j < 4) ? b0[j] : b1[j - 4];
            const float a = bias
                + bf16_to_f32(win[0][j]) * wv[j][0]
                + bf16_to_f32(win[1][j]) * wv[j][1]
                + bf16_to_f32(win[2][j]) * wv[j][2]
                + bf16_to_f32(curv[j])   * wv[j][3];
            o[j] = f32_to_bf16(bf16_to_f32(gv[j]) * a);
        }
        *(u16x8*)&sgb[roff] = o;
        win[0] = win[1]; win[1] = win[2]; win[2] = curv;
    }
}

// ---------------------------------------------------------------------------
extern "C" void kernel_launch(void* const* d_in, const int* in_sizes, int n_in,
                              void* d_out, int out_size, void* d_ws, size_t ws_size,
                              hipStream_t stream) {
    const float* x      = (const float*)d_in[0];
    const float* w_norm = (const float*)d_in[1];
    const float* W_up   = (const float*)d_in[2];
    const float* W_gate = (const float*)d_in[3];
    const float* W_down = (const float*)d_in[4];
    const float* conv_w = (const float*)d_in[5];
    const float* conv_b = (const float*)d_in[6];
    float* out = (float*)d_out;

    char* ws = (char*)d_ws;
    uint16_t* normed = (uint16_t*)ws;  ws += (size_t)M_  * D_  * 2;  // 33.5 MB
    uint16_t* WupT   = (uint16_t*)ws;  ws += (size_t)DI_ * D_  * 2;  // 16.8 MB  (adjacent:
    uint16_t* WgateT = (uint16_t*)ws;  ws += (size_t)DI_ * D_  * 2;  // 16.8 MB   fused B^T [8192][2048])
    uint16_t* WdownT = (uint16_t*)ws;  ws += (size_t)D_  * DI_ * 2;  // 16.8 MB
    uint16_t* up     = (uint16_t*)ws;  ws += (size_t)M_  * DI_ * 2;  // 67 MB
    uint16_t* sg     = (uint16_t*)ws;  ws += (size_t)M_  * DI_ * 2;  // 67 MB

    // weight transposes: W[K][N] -> WT[N][K] bf16
    transpose_bf16_kernel<<<(D_ / 32) * (DI_ / 32), 256, 0, stream>>>(W_up,   WupT,   D_,  DI_);
    transpose_bf16_kernel<<<(D_ / 32) * (DI_ / 32), 256, 0, stream>>>(W_gate, WgateT, D_,  DI_);
    transpose_bf16_kernel<<<(DI_ / 32) * (D_ / 32), 256, 0, stream>>>(W_down, WdownT, DI_, D_);

    rmsnorm_kernel<<<M_, 256, 0, stream>>>(x, w_norm, normed);

    // fused: [up | silu(gate)] = normed @ [W_up | W_gate]   (N = 2*DI_ = 8192)
    gemm8p_kernel<3><<<(M_ / 128) * ((2 * DI_) / 128), 256, 0, stream>>>(
        normed, WupT, M_, 2 * DI_, D_, nullptr, up, sg, nullptr);

    // sg = sg * (causal_dwconv(up) + bias)
    conv_mul_kernel<<<(int)(((size_t)B_ * (S_ / SCH_) * (DI_ / 8)) / 256), 256, 0, stream>>>(
        up, sg, conv_w, conv_b);

    // out = x + sg @ W_down  (f32 out, fused residual)
    gemm8p_kernel<0><<<(M_ / 128) * (D_ / 128), 256, 0, stream>>>(
        sg, WdownT, M_, D_, DI_, out, nullptr, nullptr, x);
}

// Round 18
// 487.159 us; speedup vs baseline: 1.3226x; 1.3226x over previous
//
#include <hip/hip_runtime.h>
#include <stdint.h>

// Problem constants (ConvLayer_58007828300270)
#define B_   2
#define S_   4096
#define D_   2048
#define DI_  4096
#define M_   (B_ * S_)   // 8192 rows
#define EPS_ 1e-5f
#define SCH_ 8           // conv: s-rows per thread

typedef __bf16 bf16x8 __attribute__((ext_vector_type(8)));
typedef float  f32x4  __attribute__((ext_vector_type(4)));
typedef uint16_t u16x8 __attribute__((ext_vector_type(8)));

__device__ __forceinline__ uint16_t f32_to_bf16(float f) {
    uint32_t u = __builtin_bit_cast(uint32_t, f);
    uint32_t r = (u + 0x7fffu + ((u >> 16) & 1u)) >> 16;   // RNE
    return (uint16_t)r;
}
__device__ __forceinline__ float bf16_to_f32(uint16_t h) {
    return __builtin_bit_cast(float, (uint32_t)h << 16);
}

typedef const __attribute__((address_space(1))) uint32_t* gptr_t;
typedef __attribute__((address_space(3))) uint32_t* lptr_t;

// async global->LDS, 16B per lane, dst = wave-uniform base + lane*16
__device__ __forceinline__ void gll16(const void* g, void* l) {
    __builtin_amdgcn_global_load_lds((gptr_t)g, (lptr_t)l, 16, 0, 0);
}

// ---------------------------------------------------------------------------
// Transpose + f32->bf16 convert: W[K][N] f32 -> WT[N][K] bf16. 32x32 tiles.
// ---------------------------------------------------------------------------
__global__ __launch_bounds__(256)
void transpose_bf16_kernel(const float* __restrict__ W, uint16_t* __restrict__ WT,
                           int K, int N) {
    __shared__ float tile[32][33];
    const int nb = N / 32;
    const int tn = blockIdx.x % nb;
    const int tk = blockIdx.x / nb;
    const int tx = threadIdx.x & 31;
    const int ty = threadIdx.x >> 5;          // 0..7
    const int gk = tk * 32, gn = tn * 32;
#pragma unroll
    for (int i = 0; i < 4; i++) {
        int k = ty + i * 8;
        tile[k][tx] = W[(size_t)(gk + k) * N + gn + tx];
    }
    __syncthreads();
#pragma unroll
    for (int i = 0; i < 4; i++) {
        int n = ty + i * 8;
        WT[(size_t)(gn + n) * K + gk + tx] = f32_to_bf16(tile[tx][n]);
    }
}

// ---------------------------------------------------------------------------
// RMSNorm: one block per row, 256 threads x 8 elems. f32 in -> bf16 out.
// ---------------------------------------------------------------------------
__global__ __launch_bounds__(256)
void rmsnorm_kernel(const float* __restrict__ x, const float* __restrict__ w,
                    uint16_t* __restrict__ out) {
    const int row  = blockIdx.x;
    const int tid  = threadIdx.x;
    const int lane = tid & 63, wid = tid >> 6;
    const float* xr = x + (size_t)row * D_;

    f32x4 a = *(const f32x4*)&xr[tid * 8];
    f32x4 b = *(const f32x4*)&xr[tid * 8 + 4];
    float ss = a[0]*a[0] + a[1]*a[1] + a[2]*a[2] + a[3]*a[3]
             + b[0]*b[0] + b[1]*b[1] + b[2]*b[2] + b[3]*b[3];
#pragma unroll
    for (int off = 32; off > 0; off >>= 1) ss += __shfl_xor(ss, off);

    __shared__ float red[4];
    if (lane == 0) red[wid] = ss;
    __syncthreads();
    const float tot = red[0] + red[1] + red[2] + red[3];
    const float scale = rsqrtf(tot * (1.0f / D_) + EPS_);

    f32x4 wa = *(const f32x4*)&w[tid * 8];
    f32x4 wb = *(const f32x4*)&w[tid * 8 + 4];
    u16x8 o;
#pragma unroll
    for (int j = 0; j < 4; j++) o[j]     = f32_to_bf16(a[j] * scale * wa[j]);
#pragma unroll
    for (int j = 0; j < 4; j++) o[j + 4] = f32_to_bf16(b[j] * scale * wb[j]);
    *(u16x8*)&out[(size_t)row * D_ + tid * 8] = o;
}

// ---------------------------------------------------------------------------
// 256x256 GEMM, 4 phases/K-tile (BK=64), 512 thr = 8 waves (2M x 4N).
// R14 FINAL (best measured: 487.8/487.4 us total; fused GEMM 293 us,
// MfmaUtil 42%, bank conflicts 0, FETCH 197 MB).
// Structure: 1 barrier/phase (R10: removing the read->MFMA barrier was the
// only structural win, +14us) + single vmcnt(6)/K-tile (R8 slots).
// 16x16x32 MFMA (32x32x16 measured WORSE: 4-way LDS bank conflict on b128
// column reads — only 8 XOR k-slot variants for 32 lanes; R15).
// 128^2/2-blocks-per-CU measured WORSE (R17: 392us, MfmaUtil 31% — no
// cross-block anti-phase materialized; smaller-tile overheads in full).
// Stage slots: p1: Bh0(t+1)->nxt  p2: Ah0(t+2)->cur  p3: Bh1(t+2)->cur
//              p4: Ah1(t+2)->cur; single wait end-p4 vmcnt(6) (tail 0).
// FIFO: 6 outstanding entering each tile; vmcnt(6) drains tile t+1's four
// halves before its reads. WAR per slot: 1-barrier margins, regions disjoint
// from same-phase reads (hand-traced, R13 comment block).
// Block schedule (R5/R6): XCD x owns an (nbn/8)-column B-strip (L2-resident;
// FETCH 547->197 MB measured).
// EPI: 0 = f32 out + residual add
//      3 = fused up/gate: col<DI_ -> Cb (bf16), col>=DI_ -> silu -> Cb2.
// ---------------------------------------------------------------------------
template <int EPI>
__global__ __launch_bounds__(512, 2)
void gemm8p_kernel(const uint16_t* __restrict__ A, const uint16_t* __restrict__ BT,
                   int M, int N, int K,
                   float* __restrict__ Cf, uint16_t* __restrict__ Cb,
                   uint16_t* __restrict__ Cb2, const float* __restrict__ resid) {
    __shared__ uint16_t As[2][16384];   // 2 x 32 KiB (256 rows x 64 bf16)
    __shared__ uint16_t Bs[2][16384];

    const int nbn = N >> 8;
    const int bid = blockIdx.x;
    // L2/L3-aware schedule: xcd = bid&7 owns cols [xcd*wc_, +wc_)
    const int xcd = bid & 7;
    const int j   = bid >> 3;
    const int wc_ = nbn >> 3;                 // cols per XCD; pow2
    const int wlog = 31 - __clz(wc_);
    const int g   = j >> 5;
    const int rr  = j & 31;
    const int bm  = g * (32 >> wlog) + (rr >> wlog);
    const int bn  = (xcd << wlog) + (rr & (wc_ - 1));

    const int brow = bm << 8, bcol = bn << 8;
    const int tid  = threadIdx.x;
    const int wid  = tid >> 6, lane = tid & 63;
    const int wr   = wid >> 2, wcv = wid & 3;    // 2x4 wave grid
    const int fr   = lane & 15;
    // swizzled k-offset within a 64-elem row (involution on bits 3..5)
    const int kx0 = (((lane >> 4) << 3)) ^ ((lane & 7) << 3);
    const int kx1 = kx0 ^ 32;
    // B fragment LDS rows: rho_n = (n>>1)*128 + wcv*32 + (n&1)*16 + fr
    int rhoN[4];
#pragma unroll
    for (int n = 0; n < 4; n++) rhoN[n] = ((n >> 1) << 7) + (wcv << 5) + ((n & 1) << 4) + fr;

    // staging source descriptors: call i covers LDS bytes [i*8192, i*8192+8192)
    const uint16_t* ApS[4];
    const uint16_t* BpS[4];
#pragma unroll
    for (int i = 0; i < 4; i++) {
        const int z  = (i << 13) + (wid << 10) + (lane << 4);
        const int zz = z ^ (((z >> 7) & 7) << 4);
        const int row = zz >> 7;           // LDS row = logical A row
        const int kk  = (zz >> 1) & 63;
        ApS[i] = A + (size_t)(brow + row) * K + kk;
        // B: LDS row rho -> logical row r = q*64 + h*32 + jj
        const int h = row >> 7, q = (row >> 5) & 3, jj = row & 31;
        BpS[i] = BT + (size_t)(bcol + q * 64 + h * 32 + jj) * K + kk;
    }

    f32x4 acc[8][4];
#pragma unroll
    for (int i = 0; i < 8; i++)
#pragma unroll
        for (int jn = 0; jn < 4; jn++) acc[i][jn] = (f32x4){0.f, 0.f, 0.f, 0.f};

    const int nt = K >> 6;

    // ---- prologue: 7 halves (FIFO leaves steady-state 6 in flight) ----
    gll16(ApS[0],      &As[0][0 * 4096 + wid * 512]);   // Ah0(0)
    gll16(ApS[2],      &As[0][2 * 4096 + wid * 512]);
    gll16(BpS[0],      &Bs[0][0 * 4096 + wid * 512]);   // Bh0(0)
    gll16(BpS[1],      &Bs[0][1 * 4096 + wid * 512]);
    gll16(BpS[2],      &Bs[0][2 * 4096 + wid * 512]);   // Bh1(0)
    gll16(BpS[3],      &Bs[0][3 * 4096 + wid * 512]);
    gll16(ApS[1],      &As[0][1 * 4096 + wid * 512]);   // Ah1(0)
    gll16(ApS[3],      &As[0][3 * 4096 + wid * 512]);
    gll16(ApS[0] + 64, &As[1][0 * 4096 + wid * 512]);   // Ah0(1)
    gll16(ApS[2] + 64, &As[1][2 * 4096 + wid * 512]);
    gll16(BpS[2] + 64, &Bs[1][2 * 4096 + wid * 512]);   // Bh1(1)
    gll16(BpS[3] + 64, &Bs[1][3 * 4096 + wid * 512]);
    gll16(ApS[1] + 64, &As[1][1 * 4096 + wid * 512]);   // Ah1(1)
    gll16(ApS[3] + 64, &As[1][3 * 4096 + wid * 512]);
    asm volatile("s_waitcnt vmcnt(6)" ::: "memory");     // tile 0 fully landed
    __builtin_amdgcn_s_barrier();

    bf16x8 aF[8], bF[8];

    for (int t = 0; t < nt; ++t) {
        const int cur = t & 1, nxt = cur ^ 1;
        const int kn1 = (t + 1) << 6;
        const int kn2 = (t + 2) << 6;
        const bool pf1 = (t + 1) < nt;
        const bool pf2 = (t + 2) < nt;

        // ---- p1: read A-h0 + B-h0; stage Bh0(t+1)->nxt; MFMA h0xn01
#pragma unroll
        for (int mh = 0; mh < 4; ++mh) {
            const int r = (wr << 7) + (mh << 4) + fr;
            aF[mh * 2 + 0] = *(const bf16x8*)&As[cur][r * 64 + kx0];
            aF[mh * 2 + 1] = *(const bf16x8*)&As[cur][r * 64 + kx1];
        }
#pragma unroll
        for (int n = 0; n < 2; ++n) {
            bF[n * 2 + 0] = *(const bf16x8*)&Bs[cur][rhoN[n] * 64 + kx0];
            bF[n * 2 + 1] = *(const bf16x8*)&Bs[cur][rhoN[n] * 64 + kx1];
        }
        if (pf1) {
            gll16(BpS[0] + kn1, &Bs[nxt][0 * 4096 + wid * 512]);
            gll16(BpS[1] + kn1, &Bs[nxt][1 * 4096 + wid * 512]);
        }
        __builtin_amdgcn_s_setprio(1);
#pragma unroll
        for (int mh = 0; mh < 4; ++mh)
#pragma unroll
            for (int n = 0; n < 2; ++n)
#pragma unroll
                for (int ks = 0; ks < 2; ++ks)
                    acc[mh][n] = __builtin_amdgcn_mfma_f32_16x16x32_bf16(
                        aF[mh * 2 + ks], bF[n * 2 + ks], acc[mh][n], 0, 0, 0);
        __builtin_amdgcn_s_setprio(0);
        __builtin_amdgcn_s_barrier();

        // ---- p2: read B-h1; stage Ah0(t+2)->cur; MFMA h0xn23
#pragma unroll
        for (int n = 2; n < 4; ++n) {
            bF[n * 2 + 0] = *(const bf16x8*)&Bs[cur][rhoN[n] * 64 + kx0];
            bF[n * 2 + 1] = *(const bf16x8*)&Bs[cur][rhoN[n] * 64 + kx1];
        }
        if (pf2) {
            gll16(ApS[0] + kn2, &As[cur][0 * 4096 + wid * 512]);
            gll16(ApS[2] + kn2, &As[cur][2 * 4096 + wid * 512]);
        }
        __builtin_amdgcn_s_setprio(1);
#pragma unroll
        for (int mh = 0; mh < 4; ++mh)
#pragma unroll
            for (int n = 2; n < 4; ++n)
#pragma unroll
                for (int ks = 0; ks < 2; ++ks)
                    acc[mh][n] = __builtin_amdgcn_mfma_f32_16x16x32_bf16(
                        aF[mh * 2 + ks], bF[n * 2 + ks], acc[mh][n], 0, 0, 0);
        __builtin_amdgcn_s_setprio(0);
        __builtin_amdgcn_s_barrier();

        // ---- p3: read A-h1; stage Bh1(t+2)->cur; MFMA h1xn23
#pragma unroll
        for (int mh = 0; mh < 4; ++mh) {
            const int r = (wr << 7) + 64 + (mh << 4) + fr;
            aF[mh * 2 + 0] = *(const bf16x8*)&As[cur][r * 64 + kx0];
            aF[mh * 2 + 1] = *(const bf16x8*)&As[cur][r * 64 + kx1];
        }
        if (pf2) {
            gll16(BpS[2] + kn2, &Bs[cur][2 * 4096 + wid * 512]);
            gll16(BpS[3] + kn2, &Bs[cur][3 * 4096 + wid * 512]);
        }
        __builtin_amdgcn_s_setprio(1);
#pragma unroll
        for (int mh = 0; mh < 4; ++mh)
#pragma unroll
            for (int n = 2; n < 4; ++n)
#pragma unroll
                for (int ks = 0; ks < 2; ++ks)
                    acc[4 + mh][n] = __builtin_amdgcn_mfma_f32_16x16x32_bf16(
                        aF[mh * 2 + ks], bF[n * 2 + ks], acc[4 + mh][n], 0, 0, 0);
        __builtin_amdgcn_s_setprio(0);
        __builtin_amdgcn_s_barrier();

        // ---- p4: stage Ah1(t+2)->cur; MFMA h1xn01; SINGLE wait
        if (pf2) {
            gll16(ApS[1] + kn2, &As[cur][1 * 4096 + wid * 512]);
            gll16(ApS[3] + kn2, &As[cur][3 * 4096 + wid * 512]);
        }
        __builtin_amdgcn_s_setprio(1);
#pragma unroll
        for (int mh = 0; mh < 4; ++mh)
#pragma unroll
            for (int n = 0; n < 2; ++n)
#pragma unroll
                for (int ks = 0; ks < 2; ++ks)
                    acc[4 + mh][n] = __builtin_amdgcn_mfma_f32_16x16x32_bf16(
                        aF[mh * 2 + ks], bF[n * 2 + ks], acc[4 + mh][n], 0, 0, 0);
        __builtin_amdgcn_s_setprio(0);
        if (pf2) { asm volatile("s_waitcnt vmcnt(6)" ::: "memory"); }
        else     { asm volatile("s_waitcnt vmcnt(0)" ::: "memory"); }
        __builtin_amdgcn_s_barrier();
    }

    // epilogue: C/D layout col = lane&15, row = (lane>>4)*4 + reg
    const int r0 = (lane >> 4) << 2;
    const bool upHalf = (bcol < DI_);   // block-uniform for EPI==3 (DI_%256==0)
#pragma unroll
    for (int m = 0; m < 8; ++m) {
        const int row = brow + (wr << 7) + ((m >> 2) << 6) + ((m & 3) << 4) + r0;
#pragma unroll
        for (int n = 0; n < 4; ++n) {
            const int col = bcol + (wcv << 6) + (n << 4) + fr;
#pragma unroll
            for (int r = 0; r < 4; ++r) {
                const float v = acc[m][n][r];
                if (EPI == 0) {
                    const size_t idx = (size_t)(row + r) * N + col;
                    Cf[idx] = v + resid[idx];
                } else {  // EPI == 3: fused up/gate routing
                    if (upHalf) {
                        Cb[(size_t)(row + r) * DI_ + col] = f32_to_bf16(v);
                    } else {
                        const float s = v / (1.0f + __expf(-v));
                        Cb2[(size_t)(row + r) * DI_ + (col - DI_)] = f32_to_bf16(s);
                    }
                }
            }
        }
    }
}

// ---------------------------------------------------------------------------
// Causal depthwise conv (K=4) on `up`, multiply by silu-gate (in sg),
// write gated back into sg (in place, element-wise safe).
// ---------------------------------------------------------------------------
__global__ __launch_bounds__(256)
void conv_mul_kernel(const uint16_t* __restrict__ up, uint16_t* __restrict__ sg,
                     const float* __restrict__ cw, const float* __restrict__ cb) {
    const size_t gid = (size_t)blockIdx.x * 256 + threadIdx.x;
    const int c8 = (int)(gid % (DI_ / 8));                 // channel group, fastest
    const int sc = (int)((gid / (DI_ / 8)) % (S_ / SCH_)); // s-chunk
    const int b  = (int)(gid / ((size_t)(DI_ / 8) * (S_ / SCH_)));
    const int c0 = c8 * 8;
    const int s0 = sc * SCH_;

    f32x4 wv[8];
#pragma unroll
    for (int j = 0; j < 8; j++) wv[j] = *(const f32x4*)&cw[(c0 + j) * 4];
    const f32x4 b0 = *(const f32x4*)&cb[c0];
    const f32x4 b1 = *(const f32x4*)&cb[c0 + 4];

    const uint16_t* upb = up + (size_t)b * S_ * DI_ + c0;
    uint16_t*       sgb = sg + (size_t)b * S_ * DI_ + c0;

    u16x8 win[3];
#pragma unroll
    for (int i = 0; i < 3; i++) {
        const int ss = s0 - 3 + i;
        if (ss >= 0) {
            win[i] = *(const u16x8*)&upb[(size_t)ss * DI_];
        } else {
#pragma unroll
            for (int j = 0; j < 8; j++) win[i][j] = 0;
        }
    }

#pragma unroll
    for (int st = 0; st < SCH_; ++st) {
        const size_t roff = (size_t)(s0 + st) * DI_;
        const u16x8 curv = *(const u16x8*)&upb[roff];
        const u16x8 gv   = *(const u16x8*)&sgb[roff];
        u16x8 o;
#pragma unroll
        for (int j = 0; j < 8; j++) {
            const float bias = (j < 4) ? b0[j] : b1[j - 4];
            const float a = bias
                + bf16_to_f32(win[0][j]) * wv[j][0]
                + bf16_to_f32(win[1][j]) * wv[j][1]
                + bf16_to_f32(win[2][j]) * wv[j][2]
                + bf16_to_f32(curv[j])   * wv[j][3];
            o[j] = f32_to_bf16(bf16_to_f32(gv[j]) * a);
        }
        *(u16x8*)&sgb[roff] = o;
        win[0] = win[1]; win[1] = win[2]; win[2] = curv;
    }
}

// ---------------------------------------------------------------------------
extern "C" void kernel_launch(void* const* d_in, const int* in_sizes, int n_in,
                              void* d_out, int out_size, void* d_ws, size_t ws_size,
                              hipStream_t stream) {
    const float* x      = (const float*)d_in[0];
    const float* w_norm = (const float*)d_in[1];
    const float* W_up   = (const float*)d_in[2];
    const float* W_gate = (const float*)d_in[3];
    const float* W_down = (const float*)d_in[4];
    const float* conv_w = (const float*)d_in[5];
    const float* conv_b = (const float*)d_in[6];
    float* out = (float*)d_out;

    char* ws = (char*)d_ws;
    uint16_t* normed = (uint16_t*)ws;  ws += (size_t)M_  * D_  * 2;  // 33.5 MB
    uint16_t* WupT   = (uint16_t*)ws;  ws += (size_t)DI_ * D_  * 2;  // 16.8 MB  (adjacent:
    uint16_t* WgateT = (uint16_t*)ws;  ws += (size_t)DI_ * D_  * 2;  // 16.8 MB   fused B^T [8192][2048])
    uint16_t* WdownT = (uint16_t*)ws;  ws += (size_t)D_  * DI_ * 2;  // 16.8 MB
    uint16_t* up     = (uint16_t*)ws;  ws += (size_t)M_  * DI_ * 2;  // 67 MB
    uint16_t* sg     = (uint16_t*)ws;  ws += (size_t)M_  * DI_ * 2;  // 67 MB

    // weight transposes: W[K][N] -> WT[N][K] bf16
    transpose_bf16_kernel<<<(D_ / 32) * (DI_ / 32), 256, 0, stream>>>(W_up,   WupT,   D_,  DI_);
    transpose_bf16_kernel<<<(D_ / 32) * (DI_ / 32), 256, 0, stream>>>(W_gate, WgateT, D_,  DI_);
    transpose_bf16_kernel<<<(DI_ / 32) * (D_ / 32), 256, 0, stream>>>(W_down, WdownT, DI_, D_);

    rmsnorm_kernel<<<M_, 256, 0, stream>>>(x, w_norm, normed);

    // fused: [up | silu(gate)] = normed @ [W_up | W_gate]   (N = 2*DI_ = 8192)
    gemm8p_kernel<3><<<(M_ / 256) * ((2 * DI_) / 256), 512, 0, stream>>>(
        normed, WupT, M_, 2 * DI_, D_, nullptr, up, sg, nullptr);

    // sg = sg * (causal_dwconv(up) + bias)
    conv_mul_kernel<<<(int)(((size_t)B_ * (S_ / SCH_) * (DI_ / 8)) / 256), 256, 0, stream>>>(
        up, sg, conv_w, conv_b);

    // out = x + sg @ W_down  (f32 out, fused residual)
    gemm8p_kernel<0><<<(M_ / 256) * (D_ / 256), 512, 0, stream>>>(
        sg, WdownT, M_, D_, DI_, out, nullptr, nullptr, x);
}